// Round 5
// baseline (269.634 us; speedup 1.0000x reference)
//
#include <hip/hip_runtime.h>
#include <hip/hip_bf16.h>
#include <stdint.h>

#define DMODEL 2048
#define HQ 16
#define HKV 4
#define DH 128
#define SEQT 2048
#define BATCH 2

typedef __bf16 bf16x8 __attribute__((ext_vector_type(8)));
typedef float f32x4 __attribute__((ext_vector_type(4)));
typedef float f32x16 __attribute__((ext_vector_type(16)));
typedef unsigned short u16x4 __attribute__((ext_vector_type(4)));
typedef unsigned short u16x8 __attribute__((ext_vector_type(8)));

__device__ __forceinline__ unsigned short f2bf(float x) {
  __hip_bfloat16 h = __float2bfloat16(x);
  return __builtin_bit_cast(unsigned short, h);
}
__device__ __forceinline__ unsigned int pack2(float a, float b) {
  return (unsigned int)f2bf(a) | ((unsigned int)f2bf(b) << 16);
}

__device__ __forceinline__ void gload_lds16(const void* g, void* lds) {
  __builtin_amdgcn_global_load_lds(
      (const __attribute__((address_space(1))) void*)(uintptr_t)g,
      (__attribute__((address_space(3))) void*)(uint32_t)(uintptr_t)lds,
      16, 0, 0);
}

// ---------------- fused cast f32 -> bf16 (all 5 tensors; wq pre-scaled) -----
__global__ __launch_bounds__(256) void cast_all_kernel(
    const float* __restrict__ x, const float* __restrict__ wq,
    const float* __restrict__ wk, const float* __restrict__ wv,
    const float* __restrict__ wo,
    unsigned short* __restrict__ xb, unsigned short* __restrict__ wqb,
    unsigned short* __restrict__ wkb, unsigned short* __restrict__ wvb,
    unsigned short* __restrict__ wob) {
  int i = blockIdx.x * 256 + threadIdx.x;
  const float* in; unsigned short* out; int off; float s = 1.0f;
  if (i < 1048576)      { in = x;  out = xb;  off = i; }
  else if (i < 1572864) { in = wq; out = wqb; off = i - 1048576; s = 0.1275174473f; }
  else if (i < 1703936) { in = wk; out = wkb; off = i - 1572864; }
  else if (i < 1835008) { in = wv; out = wvb; off = i - 1703936; }
  else                  { in = wo; out = wob; off = i - 1835008; }
  const float4* p = reinterpret_cast<const float4*>(in) + (size_t)off * 2;
  float4 a = p[0], b = p[1];
  u16x8 o;
  o[0] = f2bf(a.x * s); o[1] = f2bf(a.y * s); o[2] = f2bf(a.z * s); o[3] = f2bf(a.w * s);
  o[4] = f2bf(b.x * s); o[5] = f2bf(b.y * s); o[6] = f2bf(b.z * s); o[7] = f2bf(b.w * s);
  *(reinterpret_cast<u16x8*>(out) + off) = o;
}

// ---------------- GEMM body: C[m,n]=sum_k A[m,k]*B[n,k], BK=64 (2x32 halves)
template <bool OUT_BF16>
__device__ __forceinline__ void gemm_body(
    unsigned short* As, unsigned short* Bs,
    const unsigned short* __restrict__ A, const unsigned short* __restrict__ B,
    void* __restrict__ Cv, int N, int K, int row0, int col0) {
  const int tid = threadIdx.x;
  const int wave = tid >> 6, lane = tid & 63;
  const int wr = (wave >> 1) * 64, wc = (wave & 1) * 64;
  const int l15 = lane & 15, l4 = lane >> 4;
  const int srow = wave * 32 + (lane >> 2);
  const int scol = (lane & 3) * 8;

  f32x4 acc[4][4] = {};

  for (int k0 = 0; k0 < K; k0 += 64) {
#pragma unroll
    for (int h = 0; h < 2; ++h) {
      const unsigned short* gA = A + (size_t)(row0 + srow) * K + k0 + h * 32 + scol;
      gload_lds16(gA, (char*)As + h * 8192 + wave * 2048);
      gload_lds16(gA + (size_t)16 * K, (char*)As + h * 8192 + wave * 2048 + 1024);
      const unsigned short* gB = B + (size_t)(col0 + srow) * K + k0 + h * 32 + scol;
      gload_lds16(gB, (char*)Bs + h * 8192 + wave * 2048);
      gload_lds16(gB + (size_t)16 * K, (char*)Bs + h * 8192 + wave * 2048 + 1024);
    }
    __syncthreads();

    bf16x8 af[2][4], bfr[2][4];
#pragma unroll
    for (int h = 0; h < 2; ++h)
#pragma unroll
      for (int i = 0; i < 4; ++i) {
        af[h][i]  = *reinterpret_cast<const bf16x8*>(&As[h * 4096 + (wr + i * 16 + l15) * 32 + l4 * 8]);
        bfr[h][i] = *reinterpret_cast<const bf16x8*>(&Bs[h * 4096 + (wc + i * 16 + l15) * 32 + l4 * 8]);
      }
#pragma unroll
    for (int h = 0; h < 2; ++h)
#pragma unroll
      for (int i = 0; i < 4; ++i)
#pragma unroll
        for (int j = 0; j < 4; ++j)
          acc[i][j] = __builtin_amdgcn_mfma_f32_16x16x32_bf16(af[h][i], bfr[h][j], acc[i][j], 0, 0, 0);
    __syncthreads();
  }

#pragma unroll
  for (int i = 0; i < 4; ++i) {
    const int rrow = row0 + wr + i * 16 + l4 * 4;
#pragma unroll
    for (int j = 0; j < 4; ++j) {
      const int ccol = col0 + wc + j * 16 + l15;
#pragma unroll
      for (int r = 0; r < 4; ++r) {
        const size_t idx = (size_t)(rrow + r) * N + ccol;
        if constexpr (OUT_BF16)
          ((unsigned short*)Cv)[idx] = f2bf(acc[i][j][r]);
        else
          ((float*)Cv)[idx] = acc[i][j][r];
      }
    }
  }
}

// Q-proj (0..511) + K-proj (512..639) + V^T-proj (640..767), one launch
__global__ __launch_bounds__(256) void gemm_qkv(
    const unsigned short* __restrict__ xb, const unsigned short* __restrict__ wqb,
    const unsigned short* __restrict__ wkb, const unsigned short* __restrict__ wvb,
    unsigned short* __restrict__ Qb, unsigned short* __restrict__ Kb,
    unsigned short* __restrict__ VTb) {
  __shared__ alignas(16) unsigned short As[2][128 * 32];
  __shared__ alignas(16) unsigned short Bs[2][128 * 32];
  const int bid = blockIdx.x;
  if (bid < 512) {
    gemm_body<true>(&As[0][0], &Bs[0][0], xb, wqb, Qb, 2048, DMODEL,
                    (bid >> 4) * 128, (bid & 15) * 128);
  } else if (bid < 640) {
    const int r = bid - 512;
    gemm_body<true>(&As[0][0], &Bs[0][0], xb, wkb, Kb, 512, DMODEL,
                    (r >> 2) * 128, (r & 3) * 128);
  } else {
    const int r = bid - 640;
    const int tz = r & 1, ty = (r >> 1) & 15, tx = r >> 5;
    gemm_body<true>(&As[0][0], &Bs[0][0], wvb,
                    xb + (size_t)tz * SEQT * DMODEL,
                    VTb + (size_t)tz * 512 * SEQT, SEQT, DMODEL,
                    tx * 128, ty * 128);
  }
}

template <bool OUT_BF16>
__global__ __launch_bounds__(256) void gemm_bt(
    const unsigned short* __restrict__ A, const unsigned short* __restrict__ B,
    void* __restrict__ Cv, int N, int K) {
  __shared__ alignas(16) unsigned short As[2][128 * 32];
  __shared__ alignas(16) unsigned short Bs[2][128 * 32];
  gemm_body<OUT_BF16>(&As[0][0], &Bs[0][0], A, B, Cv, N, K,
                      blockIdx.x * 128, blockIdx.y * 128);
}

// ---------------- fused causal GQA flash attention ---------------------------
// Block = (b, hk, q-tile j of 32 rows); 4 waves = 4 q-heads sharing kv head.
// K in LDS (dbuf, prefetch); V direct global->reg issued early (T14).
// Swapped QK^T (split 2x4 MFMA chains), in-register online softmax (trees).
__global__ __launch_bounds__(256, 2) void attn_kernel(
    const unsigned short* __restrict__ Q, const unsigned short* __restrict__ Kc,
    const unsigned short* __restrict__ VT, unsigned short* __restrict__ AO) {
  __shared__ alignas(16) unsigned short Ks[2][16 * 512];   // 16KB per buf

  const int tid = threadIdx.x;
  const int wave = tid >> 6, lane = tid & 63;
  const int bid = blockIdx.x;
  const int round = bid >> 8, pairslot = bid & 255;
  const int bhk = pairslot & 7;              // XCD-pinned
  const int jp = pairslot >> 3;
  const int j = round ? jp : 63 - jp;        // q-tile index 0..63
  const int b = bhk >> 2, hk = bhk & 3;
  const int h = hk + wave * 4;
  const int q0 = j * 32;
  const int jt = j >> 1;
  const int lq = lane & 31, hi = lane >> 5;

  const size_t qrow = (size_t)(b * SEQT + q0 + lq);
  const unsigned short* qp = Q + qrow * (HQ * DH) + h * DH + hi * 8;
  bf16x8 qf[8];
#pragma unroll
  for (int dc = 0; dc < 8; ++dc)
    qf[dc] = *reinterpret_cast<const bf16x8*>(qp + dc * 16);

  f32x16 acc[4] = {};
  float mrun = -INFINITY, lrun = 0.f;

  const unsigned short* kbase = Kc + (size_t)b * SEQT * (HKV * DH) + hk * DH;
  const unsigned short* vrow = VT + ((size_t)b * (HKV * DH) + hk * DH + lq) * SEQT + hi * 8;

  auto STAGE_K = [&](int buf, int kvb2) {
#pragma unroll
    for (int i = 0; i < 4; ++i) {
      const int f = i * 4 + wave;            // f: sub=f>>3, dc=f&7
      const int sub = f >> 3, dc = f & 7;
      const unsigned short* g = kbase + (size_t)(kvb2 + sub * 32 + lq) * (HKV * DH) + dc * 16 + hi * 8;
      gload_lds16(g, (char*)Ks[buf] + f * 1024);
    }
  };

  STAGE_K(0, 0);
  __syncthreads();
  int cur = 0;

  for (int t = 0; t <= jt; ++t) {
    const int kvb = t * 64;
    const bool s1v = (kvb + 32 <= q0);
    const bool d0 = (kvb == q0), d1 = (kvb + 32 == q0);

    // ---- V sub0 fragments: direct global->reg, issued early ----
    bf16x8 vfa[8];
#pragma unroll
    for (int dt = 0; dt < 4; ++dt)
#pragma unroll
      for (int ks = 0; ks < 2; ++ks)
        vfa[dt * 2 + ks] = *reinterpret_cast<const bf16x8*>(
            vrow + (size_t)dt * 32 * SEQT + kvb + ks * 16);

    if (t < jt) STAGE_K(cur ^ 1, kvb + 64);

    // ---- S^T = K * Q : two independent 4-MFMA chains per sub-tile ----
    f32x16 stA = {}, stB = {}, stA1 = {}, stB1 = {};
    __builtin_amdgcn_s_setprio(1);
#pragma unroll
    for (int dc = 0; dc < 4; ++dc) {
      bf16x8 kf = *reinterpret_cast<const bf16x8*>((char*)Ks[cur] + dc * 1024 + lane * 16);
      stA = __builtin_amdgcn_mfma_f32_32x32x16_bf16(kf, qf[dc], stA, 0, 0, 0);
    }
#pragma unroll
    for (int dc = 4; dc < 8; ++dc) {
      bf16x8 kf = *reinterpret_cast<const bf16x8*>((char*)Ks[cur] + dc * 1024 + lane * 16);
      stB = __builtin_amdgcn_mfma_f32_32x32x16_bf16(kf, qf[dc], stB, 0, 0, 0);
    }
    if (s1v) {
#pragma unroll
      for (int dc = 0; dc < 4; ++dc) {
        bf16x8 kf = *reinterpret_cast<const bf16x8*>((char*)Ks[cur] + (8 + dc) * 1024 + lane * 16);
        stA1 = __builtin_amdgcn_mfma_f32_32x32x16_bf16(kf, qf[dc], stA1, 0, 0, 0);
      }
#pragma unroll
      for (int dc = 4; dc < 8; ++dc) {
        bf16x8 kf = *reinterpret_cast<const bf16x8*>((char*)Ks[cur] + (8 + dc) * 1024 + lane * 16);
        stB1 = __builtin_amdgcn_mfma_f32_32x32x16_bf16(kf, qf[dc], stB1, 0, 0, 0);
      }
    }
    __builtin_amdgcn_s_setprio(0);

    // ---- V sub1 fragments (only needed when s1v) ----
    bf16x8 vfb[8];
    if (s1v) {
#pragma unroll
      for (int dt = 0; dt < 4; ++dt)
#pragma unroll
        for (int ks = 0; ks < 2; ++ks)
          vfb[dt * 2 + ks] = *reinterpret_cast<const bf16x8*>(
              vrow + (size_t)dt * 32 * SEQT + kvb + 32 + ks * 16);
    }

    // ---- combine + mask + online softmax (trees) ----
    float p0[16], p1[16];
#pragma unroll
    for (int r = 0; r < 16; ++r) p0[r] = stA[r] + stB[r];
    if (d0) {
#pragma unroll
      for (int r = 0; r < 16; ++r) {
        const int srw = (r & 3) + 8 * (r >> 2) + 4 * hi;
        if (srw > lq) p0[r] = -INFINITY;
      }
    }
    float m0, m1 = -INFINITY;
    {
      float a = fmaxf(fmaxf(p0[0], p0[1]), fmaxf(p0[2], p0[3]));
      float bm = fmaxf(fmaxf(p0[4], p0[5]), fmaxf(p0[6], p0[7]));
      float c = fmaxf(fmaxf(p0[8], p0[9]), fmaxf(p0[10], p0[11]));
      float dm = fmaxf(fmaxf(p0[12], p0[13]), fmaxf(p0[14], p0[15]));
      m0 = fmaxf(fmaxf(a, bm), fmaxf(c, dm));
    }
    if (s1v) {
#pragma unroll
      for (int r = 0; r < 16; ++r) p1[r] = stA1[r] + stB1[r];
      if (d1) {
#pragma unroll
        for (int r = 0; r < 16; ++r) {
          const int srw = (r & 3) + 8 * (r >> 2) + 4 * hi;
          if (srw > lq) p1[r] = -INFINITY;
        }
      }
      float a = fmaxf(fmaxf(p1[0], p1[1]), fmaxf(p1[2], p1[3]));
      float bm = fmaxf(fmaxf(p1[4], p1[5]), fmaxf(p1[6], p1[7]));
      float c = fmaxf(fmaxf(p1[8], p1[9]), fmaxf(p1[10], p1[11]));
      float dm = fmaxf(fmaxf(p1[12], p1[13]), fmaxf(p1[14], p1[15]));
      m1 = fmaxf(fmaxf(a, bm), fmaxf(c, dm));
    }
    float tmax = fmaxf(m0, m1);
    tmax = fmaxf(tmax, __shfl_xor(tmax, 32));
    if (!__all(tmax <= mrun)) {
      const float mnew = fmaxf(mrun, tmax);
      const float fsc = __builtin_amdgcn_exp2f(mrun - mnew);
      lrun *= fsc;
#pragma unroll
      for (int dt = 0; dt < 4; ++dt)
#pragma unroll
        for (int r = 0; r < 16; ++r) acc[dt][r] *= fsc;
      mrun = mnew;
    }
    float psum;
    {
#pragma unroll
      for (int r = 0; r < 16; ++r) p0[r] = __builtin_amdgcn_exp2f(p0[r] - mrun);
      float t0 = (p0[0] + p0[1]) + (p0[2] + p0[3]);
      float t1 = (p0[4] + p0[5]) + (p0[6] + p0[7]);
      float t2 = (p0[8] + p0[9]) + (p0[10] + p0[11]);
      float t3 = (p0[12] + p0[13]) + (p0[14] + p0[15]);
      psum = (t0 + t1) + (t2 + t3);
    }
    if (s1v) {
#pragma unroll
      for (int r = 0; r < 16; ++r) p1[r] = __builtin_amdgcn_exp2f(p1[r] - mrun);
      float t0 = (p1[0] + p1[1]) + (p1[2] + p1[3]);
      float t1 = (p1[4] + p1[5]) + (p1[6] + p1[7]);
      float t2 = (p1[8] + p1[9]) + (p1[10] + p1[11]);
      float t3 = (p1[12] + p1[13]) + (p1[14] + p1[15]);
      psum += (t0 + t1) + (t2 + t3);
    }
    psum += __shfl_xor(psum, 32);
    lrun += psum;

    // ---- pack P^T into B-operand fragments ----
    union { unsigned int u[4]; bf16x8 v; } pf0, pf1, pf2, pf3;
    {
      unsigned int x0 = pack2(p0[0], p0[1]),  x1 = pack2(p0[2], p0[3]);
      unsigned int x2 = pack2(p0[4], p0[5]),  x3 = pack2(p0[6], p0[7]);
      unsigned int x4 = pack2(p0[8], p0[9]),  x5 = pack2(p0[10], p0[11]);
      unsigned int x6 = pack2(p0[12], p0[13]), x7 = pack2(p0[14], p0[15]);
      unsigned int x0s = __shfl_xor(x0, 32), x1s = __shfl_xor(x1, 32);
      unsigned int x2s = __shfl_xor(x2, 32), x3s = __shfl_xor(x3, 32);
      unsigned int x4s = __shfl_xor(x4, 32), x5s = __shfl_xor(x5, 32);
      unsigned int x6s = __shfl_xor(x6, 32), x7s = __shfl_xor(x7, 32);
      pf0.u[0] = hi ? x2s : x0;  pf0.u[1] = hi ? x3s : x1;
      pf0.u[2] = hi ? x2  : x0s; pf0.u[3] = hi ? x3  : x1s;
      pf1.u[0] = hi ? x6s : x4;  pf1.u[1] = hi ? x7s : x5;
      pf1.u[2] = hi ? x6  : x4s; pf1.u[3] = hi ? x7  : x5s;
    }
    if (s1v) {
      unsigned int x0 = pack2(p1[0], p1[1]),  x1 = pack2(p1[2], p1[3]);
      unsigned int x2 = pack2(p1[4], p1[5]),  x3 = pack2(p1[6], p1[7]);
      unsigned int x4 = pack2(p1[8], p1[9]),  x5 = pack2(p1[10], p1[11]);
      unsigned int x6 = pack2(p1[12], p1[13]), x7 = pack2(p1[14], p1[15]);
      unsigned int x0s = __shfl_xor(x0, 32), x1s = __shfl_xor(x1, 32);
      unsigned int x2s = __shfl_xor(x2, 32), x3s = __shfl_xor(x3, 32);
      unsigned int x4s = __shfl_xor(x4, 32), x5s = __shfl_xor(x5, 32);
      unsigned int x6s = __shfl_xor(x6, 32), x7s = __shfl_xor(x7, 32);
      pf2.u[0] = hi ? x2s : x0;  pf2.u[1] = hi ? x3s : x1;
      pf2.u[2] = hi ? x2  : x0s; pf2.u[3] = hi ? x3  : x1s;
      pf3.u[0] = hi ? x6s : x4;  pf3.u[1] = hi ? x7s : x5;
      pf3.u[2] = hi ? x6  : x4s; pf3.u[3] = hi ? x7  : x5s;
    }

    // ---- O^T[d][q] += V^T[d][s] * P^T[s][q] (V from registers) ----
    __builtin_amdgcn_s_setprio(1);
#pragma unroll
    for (int dt = 0; dt < 4; ++dt) {
      acc[dt] = __builtin_amdgcn_mfma_f32_32x32x16_bf16(vfa[dt * 2 + 0], pf0.v, acc[dt], 0, 0, 0);
      acc[dt] = __builtin_amdgcn_mfma_f32_32x32x16_bf16(vfa[dt * 2 + 1], pf1.v, acc[dt], 0, 0, 0);
    }
    if (s1v) {
#pragma unroll
      for (int dt = 0; dt < 4; ++dt) {
        acc[dt] = __builtin_amdgcn_mfma_f32_32x32x16_bf16(vfb[dt * 2 + 0], pf2.v, acc[dt], 0, 0, 0);
        acc[dt] = __builtin_amdgcn_mfma_f32_32x32x16_bf16(vfb[dt * 2 + 1], pf3.v, acc[dt], 0, 0, 0);
      }
    }
    __builtin_amdgcn_s_setprio(0);
    __syncthreads();
    cur ^= 1;
  }

  const float inv = 1.f / lrun;
  unsigned short* op = AO + qrow * (HQ * DH) + h * DH;
#pragma unroll
  for (int dt = 0; dt < 4; ++dt) {
#pragma unroll
    for (int g2 = 0; g2 < 4; ++g2) {
      u16x4 w;
#pragma unroll
      for (int jj = 0; jj < 4; ++jj) w[jj] = f2bf(acc[dt][g2 * 4 + jj] * inv);
      *reinterpret_cast<u16x4*>(op + dt * 32 + g2 * 8 + 4 * hi) = w;
    }
  }
}

// ---------------- launch ----------------------------------------------------
extern "C" void kernel_launch(void* const* d_in, const int* in_sizes, int n_in,
                              void* d_out, int out_size, void* d_ws, size_t ws_size,
                              hipStream_t stream) {
  const float* x  = (const float*)d_in[0];
  const float* wq = (const float*)d_in[1];
  const float* wk = (const float*)d_in[2];
  const float* wv = (const float*)d_in[3];
  const float* wo = (const float*)d_in[4];
  float* out = (float*)d_out;

  const size_t N_X  = (size_t)BATCH * SEQT * DMODEL;
  const size_t N_WQ = (size_t)HQ * DH * DMODEL;
  const size_t N_WK = (size_t)HKV * DH * DMODEL;
  const size_t N_Q  = (size_t)BATCH * SEQT * HQ * DH;
  const size_t N_K  = (size_t)BATCH * SEQT * HKV * DH;

  unsigned short* xb  = (unsigned short*)d_ws;
  unsigned short* wqb = xb  + N_X;
  unsigned short* wkb = wqb + N_WQ;
  unsigned short* wvb = wkb + N_WK;
  unsigned short* wob = wvb + N_WK;
  unsigned short* Qb  = wob + N_WQ;
  unsigned short* Kb  = Qb  + N_Q;
  unsigned short* VTb = Kb  + N_K;
  unsigned short* AOb = VTb + N_K;

  cast_all_kernel<<<dim3(9216), dim3(256), 0, stream>>>(
      x, wq, wk, wv, wo, xb, wqb, wkb, wvb, wob);

  gemm_qkv<<<dim3(768), 256, 0, stream>>>(xb, wqb, wkb, wvb, Qb, Kb, VTb);
  attn_kernel<<<dim3(512, 1, 1), 256, 0, stream>>>(Qb, Kb, VTb, AOb);
  gemm_bt<false><<<dim3(32, 16, 1), 256, 0, stream>>>(AOb, wob, out, 2048, DMODEL);
}

// Round 6
// 190.999 us; speedup vs baseline: 1.4117x; 1.4117x over previous
//
#include <hip/hip_runtime.h>
#include <hip/hip_bf16.h>
#include <stdint.h>

#define DMODEL 2048
#define HQ 16
#define HKV 4
#define DH 128
#define SEQT 2048
#define BATCH 2

typedef __bf16 bf16x8 __attribute__((ext_vector_type(8)));
typedef float f32x4 __attribute__((ext_vector_type(4)));
typedef float f32x16 __attribute__((ext_vector_type(16)));
typedef unsigned short u16x4 __attribute__((ext_vector_type(4)));
typedef unsigned short u16x8 __attribute__((ext_vector_type(8)));
typedef unsigned int u32x2 __attribute__((ext_vector_type(2)));

__device__ __forceinline__ unsigned short f2bf(float x) {
  __hip_bfloat16 h = __float2bfloat16(x);
  return __builtin_bit_cast(unsigned short, h);
}
// packed bf16 convert: lo=bf16(a), hi=bf16(b) -- one VALU op (T12 half)
__device__ __forceinline__ unsigned int cvtpk(float a, float b) {
  unsigned int r;
  asm("v_cvt_pk_bf16_f32 %0, %1, %2" : "=v"(r) : "v"(a), "v"(b));
  return r;
}

__device__ __forceinline__ void gload_lds16(const void* g, void* lds) {
  __builtin_amdgcn_global_load_lds(
      (const __attribute__((address_space(1))) void*)(uintptr_t)g,
      (__attribute__((address_space(3))) void*)(uint32_t)(uintptr_t)lds,
      16, 0, 0);
}

// ---------------- fused cast f32 -> bf16 (all 5 tensors; wq pre-scaled) -----
__global__ __launch_bounds__(256) void cast_all_kernel(
    const float* __restrict__ x, const float* __restrict__ wq,
    const float* __restrict__ wk, const float* __restrict__ wv,
    const float* __restrict__ wo,
    unsigned short* __restrict__ xb, unsigned short* __restrict__ wqb,
    unsigned short* __restrict__ wkb, unsigned short* __restrict__ wvb,
    unsigned short* __restrict__ wob) {
  int i = blockIdx.x * 256 + threadIdx.x;
  const float* in; unsigned short* out; int off; float s = 1.0f;
  if (i < 1048576)      { in = x;  out = xb;  off = i; }
  else if (i < 1572864) { in = wq; out = wqb; off = i - 1048576; s = 0.1275174473f; }
  else if (i < 1703936) { in = wk; out = wkb; off = i - 1572864; }
  else if (i < 1835008) { in = wv; out = wvb; off = i - 1703936; }
  else                  { in = wo; out = wob; off = i - 1835008; }
  const float4* p = reinterpret_cast<const float4*>(in) + (size_t)off * 2;
  float4 a = p[0], b = p[1];
  u16x8 o;
  o[0] = f2bf(a.x * s); o[1] = f2bf(a.y * s); o[2] = f2bf(a.z * s); o[3] = f2bf(a.w * s);
  o[4] = f2bf(b.x * s); o[5] = f2bf(b.y * s); o[6] = f2bf(b.z * s); o[7] = f2bf(b.w * s);
  *(reinterpret_cast<u16x8*>(out) + off) = o;
}

// ---------------- GEMM body: C[m,n]=sum_k A[m,k]*B[n,k], BK=64 (2x32 halves)
template <bool OUT_BF16>
__device__ __forceinline__ void gemm_body(
    unsigned short* As, unsigned short* Bs,
    const unsigned short* __restrict__ A, const unsigned short* __restrict__ B,
    void* __restrict__ Cv, int N, int K, int row0, int col0) {
  const int tid = threadIdx.x;
  const int wave = tid >> 6, lane = tid & 63;
  const int wr = (wave >> 1) * 64, wc = (wave & 1) * 64;
  const int l15 = lane & 15, l4 = lane >> 4;
  const int srow = wave * 32 + (lane >> 2);
  const int scol = (lane & 3) * 8;

  f32x4 acc[4][4] = {};

  for (int k0 = 0; k0 < K; k0 += 64) {
#pragma unroll
    for (int h = 0; h < 2; ++h) {
      const unsigned short* gA = A + (size_t)(row0 + srow) * K + k0 + h * 32 + scol;
      gload_lds16(gA, (char*)As + h * 8192 + wave * 2048);
      gload_lds16(gA + (size_t)16 * K, (char*)As + h * 8192 + wave * 2048 + 1024);
      const unsigned short* gB = B + (size_t)(col0 + srow) * K + k0 + h * 32 + scol;
      gload_lds16(gB, (char*)Bs + h * 8192 + wave * 2048);
      gload_lds16(gB + (size_t)16 * K, (char*)Bs + h * 8192 + wave * 2048 + 1024);
    }
    __syncthreads();

    bf16x8 af[2][4], bfr[2][4];
#pragma unroll
    for (int h = 0; h < 2; ++h)
#pragma unroll
      for (int i = 0; i < 4; ++i) {
        af[h][i]  = *reinterpret_cast<const bf16x8*>(&As[h * 4096 + (wr + i * 16 + l15) * 32 + l4 * 8]);
        bfr[h][i] = *reinterpret_cast<const bf16x8*>(&Bs[h * 4096 + (wc + i * 16 + l15) * 32 + l4 * 8]);
      }
#pragma unroll
    for (int h = 0; h < 2; ++h)
#pragma unroll
      for (int i = 0; i < 4; ++i)
#pragma unroll
        for (int j = 0; j < 4; ++j)
          acc[i][j] = __builtin_amdgcn_mfma_f32_16x16x32_bf16(af[h][i], bfr[h][j], acc[i][j], 0, 0, 0);
    __syncthreads();
  }

#pragma unroll
  for (int i = 0; i < 4; ++i) {
    const int rrow = row0 + wr + i * 16 + l4 * 4;
#pragma unroll
    for (int j = 0; j < 4; ++j) {
      const int ccol = col0 + wc + j * 16 + l15;
#pragma unroll
      for (int r = 0; r < 4; ++r) {
        const size_t idx = (size_t)(rrow + r) * N + ccol;
        if constexpr (OUT_BF16)
          ((unsigned short*)Cv)[idx] = f2bf(acc[i][j][r]);
        else
          ((float*)Cv)[idx] = acc[i][j][r];
      }
    }
  }
}

// Q-proj (0..511) + K-proj (512..639) + V^T-proj (640..767), one launch
__global__ __launch_bounds__(256) void gemm_qkv(
    const unsigned short* __restrict__ xb, const unsigned short* __restrict__ wqb,
    const unsigned short* __restrict__ wkb, const unsigned short* __restrict__ wvb,
    unsigned short* __restrict__ Qb, unsigned short* __restrict__ Kb,
    unsigned short* __restrict__ VTb) {
  __shared__ alignas(16) unsigned short As[2][128 * 32];
  __shared__ alignas(16) unsigned short Bs[2][128 * 32];
  const int bid = blockIdx.x;
  if (bid < 512) {
    gemm_body<true>(&As[0][0], &Bs[0][0], xb, wqb, Qb, 2048, DMODEL,
                    (bid >> 4) * 128, (bid & 15) * 128);
  } else if (bid < 640) {
    const int r = bid - 512;
    gemm_body<true>(&As[0][0], &Bs[0][0], xb, wkb, Kb, 512, DMODEL,
                    (r >> 2) * 128, (r & 3) * 128);
  } else {
    const int r = bid - 640;
    const int tz = r & 1, ty = (r >> 1) & 15, tx = r >> 5;
    gemm_body<true>(&As[0][0], &Bs[0][0], wvb,
                    xb + (size_t)tz * SEQT * DMODEL,
                    VTb + (size_t)tz * 512 * SEQT, SEQT, DMODEL,
                    tx * 128, ty * 128);
  }
}

template <bool OUT_BF16>
__global__ __launch_bounds__(256) void gemm_bt(
    const unsigned short* __restrict__ A, const unsigned short* __restrict__ B,
    void* __restrict__ Cv, int N, int K) {
  __shared__ alignas(16) unsigned short As[2][128 * 32];
  __shared__ alignas(16) unsigned short Bs[2][128 * 32];
  gemm_body<OUT_BF16>(&As[0][0], &Bs[0][0], A, B, Cv, N, K,
                      blockIdx.x * 128, blockIdx.y * 128);
}

// ---------------- fused causal GQA flash attention ---------------------------
// Block = (b, hk, q-tile j of 32 rows); 4 waves = 4 q-heads sharing kv head.
// K,V double-buffered in LDS via global_load_lds (coalesced per-lane sources),
// prefetch next tile before computing current; 1 barrier/tile. Swapped QK^T
// (2x4 split MFMA chains), in-register online softmax (trees, defer-max),
// cvt_pk bf16 packing, PV from lane-linear LDS fragments.
__global__ __launch_bounds__(256, 2) void attn_kernel(
    const unsigned short* __restrict__ Q, const unsigned short* __restrict__ Kc,
    const unsigned short* __restrict__ VT, unsigned short* __restrict__ AO) {
  __shared__ alignas(16) unsigned short Ks[2][16 * 512];   // 16KB per buf
  __shared__ alignas(16) unsigned short Vs[2][16 * 512];

  const int tid = threadIdx.x;
  const int wave = tid >> 6, lane = tid & 63;
  const int bid = blockIdx.x;
  const int round = bid >> 8, pairslot = bid & 255;
  const int bhk = pairslot & 7;              // XCD-pinned
  const int jp = pairslot >> 3;
  const int j = round ? jp : 63 - jp;        // q-tile index 0..63
  const int b = bhk >> 2, hk = bhk & 3;
  const int h = hk + wave * 4;
  const int q0 = j * 32;
  const int jt = j >> 1;
  const int lq = lane & 31, hi = lane >> 5;

  const size_t qrow = (size_t)(b * SEQT + q0 + lq);
  const unsigned short* qp = Q + qrow * (HQ * DH) + h * DH + hi * 8;
  bf16x8 qf[8];
#pragma unroll
  for (int dc = 0; dc < 8; ++dc)
    qf[dc] = *reinterpret_cast<const bf16x8*>(qp + dc * 16);

  f32x16 acc[4] = {};
  float mrun = -INFINITY, lrun = 0.f;

  const unsigned short* kbase = Kc + (size_t)b * SEQT * (HKV * DH) + hk * DH;
  const unsigned short* vtb = VT + ((size_t)b * (HKV * DH) + hk * DH) * SEQT;

  auto STAGE = [&](int buf, int kvb2) {
#pragma unroll
    for (int i = 0; i < 4; ++i) {
      const int f = i * 4 + wave;            // K frag: sub=f>>3, dc=f&7
      const int sub = f >> 3, dc = f & 7;
      const unsigned short* g = kbase + (size_t)(kvb2 + sub * 32 + lq) * (HKV * DH) + dc * 16 + hi * 8;
      gload_lds16(g, (char*)Ks[buf] + f * 1024);
    }
#pragma unroll
    for (int i = 0; i < 4; ++i) {
      const int f = i * 4 + wave;            // V frag: dt=f>>2, ks=f&3
      const int dt = f >> 2, ks = f & 3;
      const unsigned short* g = vtb + (size_t)(dt * 32 + lq) * SEQT + kvb2 + ks * 16 + hi * 8;
      gload_lds16(g, (char*)Vs[buf] + f * 1024);
    }
  };

  STAGE(0, 0);
  __syncthreads();
  int cur = 0;

  for (int t = 0; t <= jt; ++t) {
    const int kvb = t * 64;
    if (t < jt) STAGE(cur ^ 1, kvb + 64);
    const bool s1v = (kvb + 32 <= q0);
    const bool d0 = (kvb == q0), d1 = (kvb + 32 == q0);
    const char* ksb = (const char*)Ks[cur];
    const char* vsb = (const char*)Vs[cur];

    // ---- S^T = K * Q : two independent 4-MFMA chains per 32-kv sub-tile ----
    f32x16 stA = {}, stB = {}, stA1 = {}, stB1 = {};
    __builtin_amdgcn_s_setprio(1);
#pragma unroll
    for (int dc = 0; dc < 4; ++dc) {
      bf16x8 kf = *reinterpret_cast<const bf16x8*>(ksb + dc * 1024 + lane * 16);
      stA = __builtin_amdgcn_mfma_f32_32x32x16_bf16(kf, qf[dc], stA, 0, 0, 0);
    }
#pragma unroll
    for (int dc = 4; dc < 8; ++dc) {
      bf16x8 kf = *reinterpret_cast<const bf16x8*>(ksb + dc * 1024 + lane * 16);
      stB = __builtin_amdgcn_mfma_f32_32x32x16_bf16(kf, qf[dc], stB, 0, 0, 0);
    }
    if (s1v) {
#pragma unroll
      for (int dc = 0; dc < 4; ++dc) {
        bf16x8 kf = *reinterpret_cast<const bf16x8*>(ksb + (8 + dc) * 1024 + lane * 16);
        stA1 = __builtin_amdgcn_mfma_f32_32x32x16_bf16(kf, qf[dc], stA1, 0, 0, 0);
      }
#pragma unroll
      for (int dc = 4; dc < 8; ++dc) {
        bf16x8 kf = *reinterpret_cast<const bf16x8*>(ksb + (8 + dc) * 1024 + lane * 16);
        stB1 = __builtin_amdgcn_mfma_f32_32x32x16_bf16(kf, qf[dc], stB1, 0, 0, 0);
      }
    }
    __builtin_amdgcn_s_setprio(0);

    // ---- combine + mask + online softmax (trees, defer-max) ----
    float p0[16], p1[16];
#pragma unroll
    for (int r = 0; r < 16; ++r) p0[r] = stA[r] + stB[r];
    if (d0) {
#pragma unroll
      for (int r = 0; r < 16; ++r) {
        const int srw = (r & 3) + 8 * (r >> 2) + 4 * hi;
        if (srw > lq) p0[r] = -INFINITY;
      }
    }
    float m0, m1 = -INFINITY;
    {
      float a = fmaxf(fmaxf(p0[0], p0[1]), fmaxf(p0[2], p0[3]));
      float bm = fmaxf(fmaxf(p0[4], p0[5]), fmaxf(p0[6], p0[7]));
      float c = fmaxf(fmaxf(p0[8], p0[9]), fmaxf(p0[10], p0[11]));
      float dm = fmaxf(fmaxf(p0[12], p0[13]), fmaxf(p0[14], p0[15]));
      m0 = fmaxf(fmaxf(a, bm), fmaxf(c, dm));
    }
    if (s1v) {
#pragma unroll
      for (int r = 0; r < 16; ++r) p1[r] = stA1[r] + stB1[r];
      if (d1) {
#pragma unroll
        for (int r = 0; r < 16; ++r) {
          const int srw = (r & 3) + 8 * (r >> 2) + 4 * hi;
          if (srw > lq) p1[r] = -INFINITY;
        }
      }
      float a = fmaxf(fmaxf(p1[0], p1[1]), fmaxf(p1[2], p1[3]));
      float bm = fmaxf(fmaxf(p1[4], p1[5]), fmaxf(p1[6], p1[7]));
      float c = fmaxf(fmaxf(p1[8], p1[9]), fmaxf(p1[10], p1[11]));
      float dm = fmaxf(fmaxf(p1[12], p1[13]), fmaxf(p1[14], p1[15]));
      m1 = fmaxf(fmaxf(a, bm), fmaxf(c, dm));
    }
    float tmax = fmaxf(m0, m1);
    tmax = fmaxf(tmax, __shfl_xor(tmax, 32));
    if (!__all(tmax <= mrun)) {
      const float mnew = fmaxf(mrun, tmax);
      const float fsc = __builtin_amdgcn_exp2f(mrun - mnew);
      lrun *= fsc;
#pragma unroll
      for (int dt = 0; dt < 4; ++dt)
#pragma unroll
        for (int r = 0; r < 16; ++r) acc[dt][r] *= fsc;
      mrun = mnew;
    }
    float psum;
    {
#pragma unroll
      for (int r = 0; r < 16; ++r) p0[r] = __builtin_amdgcn_exp2f(p0[r] - mrun);
      float t0 = (p0[0] + p0[1]) + (p0[2] + p0[3]);
      float t1 = (p0[4] + p0[5]) + (p0[6] + p0[7]);
      float t2 = (p0[8] + p0[9]) + (p0[10] + p0[11]);
      float t3 = (p0[12] + p0[13]) + (p0[14] + p0[15]);
      psum = (t0 + t1) + (t2 + t3);
    }
    if (s1v) {
#pragma unroll
      for (int r = 0; r < 16; ++r) p1[r] = __builtin_amdgcn_exp2f(p1[r] - mrun);
      float t0 = (p1[0] + p1[1]) + (p1[2] + p1[3]);
      float t1 = (p1[4] + p1[5]) + (p1[6] + p1[7]);
      float t2 = (p1[8] + p1[9]) + (p1[10] + p1[11]);
      float t3 = (p1[12] + p1[13]) + (p1[14] + p1[15]);
      psum += (t0 + t1) + (t2 + t3);
    }

    // ---- pack P^T into B-operand fragments (cvt_pk + half-swap via shfl) ----
    union { unsigned int u[4]; bf16x8 v; } pf0, pf1, pf2, pf3;
    {
      unsigned int x0 = cvtpk(p0[0], p0[1]),  x1 = cvtpk(p0[2], p0[3]);
      unsigned int x2 = cvtpk(p0[4], p0[5]),  x3 = cvtpk(p0[6], p0[7]);
      unsigned int x4 = cvtpk(p0[8], p0[9]),  x5 = cvtpk(p0[10], p0[11]);
      unsigned int x6 = cvtpk(p0[12], p0[13]), x7 = cvtpk(p0[14], p0[15]);
      unsigned int x0s = __shfl_xor(x0, 32), x1s = __shfl_xor(x1, 32);
      unsigned int x2s = __shfl_xor(x2, 32), x3s = __shfl_xor(x3, 32);
      unsigned int x4s = __shfl_xor(x4, 32), x5s = __shfl_xor(x5, 32);
      unsigned int x6s = __shfl_xor(x6, 32), x7s = __shfl_xor(x7, 32);
      pf0.u[0] = hi ? x2s : x0;  pf0.u[1] = hi ? x3s : x1;
      pf0.u[2] = hi ? x2  : x0s; pf0.u[3] = hi ? x3  : x1s;
      pf1.u[0] = hi ? x6s : x4;  pf1.u[1] = hi ? x7s : x5;
      pf1.u[2] = hi ? x6  : x4s; pf1.u[3] = hi ? x7  : x5s;
    }
    if (s1v) {
      unsigned int x0 = cvtpk(p1[0], p1[1]),  x1 = cvtpk(p1[2], p1[3]);
      unsigned int x2 = cvtpk(p1[4], p1[5]),  x3 = cvtpk(p1[6], p1[7]);
      unsigned int x4 = cvtpk(p1[8], p1[9]),  x5 = cvtpk(p1[10], p1[11]);
      unsigned int x6 = cvtpk(p1[12], p1[13]), x7 = cvtpk(p1[14], p1[15]);
      unsigned int x0s = __shfl_xor(x0, 32), x1s = __shfl_xor(x1, 32);
      unsigned int x2s = __shfl_xor(x2, 32), x3s = __shfl_xor(x3, 32);
      unsigned int x4s = __shfl_xor(x4, 32), x5s = __shfl_xor(x5, 32);
      unsigned int x6s = __shfl_xor(x6, 32), x7s = __shfl_xor(x7, 32);
      pf2.u[0] = hi ? x2s : x0;  pf2.u[1] = hi ? x3s : x1;
      pf2.u[2] = hi ? x2  : x0s; pf2.u[3] = hi ? x3  : x1s;
      pf3.u[0] = hi ? x6s : x4;  pf3.u[1] = hi ? x7s : x5;
      pf3.u[2] = hi ? x6  : x4s; pf3.u[3] = hi ? x7  : x5s;
    }
    psum += __shfl_xor(psum, 32);
    lrun += psum;

    // ---- O^T[d][q] += V^T[d][s] * P^T[s][q] ----
    __builtin_amdgcn_s_setprio(1);
#pragma unroll
    for (int dt = 0; dt < 4; ++dt) {
      bf16x8 v0 = *reinterpret_cast<const bf16x8*>(vsb + (dt * 4 + 0) * 1024 + lane * 16);
      bf16x8 v1 = *reinterpret_cast<const bf16x8*>(vsb + (dt * 4 + 1) * 1024 + lane * 16);
      acc[dt] = __builtin_amdgcn_mfma_f32_32x32x16_bf16(v0, pf0.v, acc[dt], 0, 0, 0);
      acc[dt] = __builtin_amdgcn_mfma_f32_32x32x16_bf16(v1, pf1.v, acc[dt], 0, 0, 0);
    }
    if (s1v) {
#pragma unroll
      for (int dt = 0; dt < 4; ++dt) {
        bf16x8 v2 = *reinterpret_cast<const bf16x8*>(vsb + (dt * 4 + 2) * 1024 + lane * 16);
        bf16x8 v3 = *reinterpret_cast<const bf16x8*>(vsb + (dt * 4 + 3) * 1024 + lane * 16);
        acc[dt] = __builtin_amdgcn_mfma_f32_32x32x16_bf16(v2, pf2.v, acc[dt], 0, 0, 0);
        acc[dt] = __builtin_amdgcn_mfma_f32_32x32x16_bf16(v3, pf3.v, acc[dt], 0, 0, 0);
      }
    }
    __builtin_amdgcn_s_setprio(0);
    __syncthreads();
    cur ^= 1;
  }

  const float inv = 1.f / lrun;
  unsigned short* op = AO + qrow * (HQ * DH) + h * DH;
#pragma unroll
  for (int dt = 0; dt < 4; ++dt) {
#pragma unroll
    for (int g2 = 0; g2 < 4; ++g2) {
      u32x2 w;
      w[0] = cvtpk(acc[dt][g2 * 4 + 0] * inv, acc[dt][g2 * 4 + 1] * inv);
      w[1] = cvtpk(acc[dt][g2 * 4 + 2] * inv, acc[dt][g2 * 4 + 3] * inv);
      *reinterpret_cast<u32x2*>(op + dt * 32 + g2 * 8 + 4 * hi) = w;
    }
  }
}

// ---------------- launch ----------------------------------------------------
extern "C" void kernel_launch(void* const* d_in, const int* in_sizes, int n_in,
                              void* d_out, int out_size, void* d_ws, size_t ws_size,
                              hipStream_t stream) {
  const float* x  = (const float*)d_in[0];
  const float* wq = (const float*)d_in[1];
  const float* wk = (const float*)d_in[2];
  const float* wv = (const float*)d_in[3];
  const float* wo = (const float*)d_in[4];
  float* out = (float*)d_out;

  const size_t N_X  = (size_t)BATCH * SEQT * DMODEL;
  const size_t N_WQ = (size_t)HQ * DH * DMODEL;
  const size_t N_WK = (size_t)HKV * DH * DMODEL;
  const size_t N_Q  = (size_t)BATCH * SEQT * HQ * DH;
  const size_t N_K  = (size_t)BATCH * SEQT * HKV * DH;

  unsigned short* xb  = (unsigned short*)d_ws;
  unsigned short* wqb = xb  + N_X;
  unsigned short* wkb = wqb + N_WQ;
  unsigned short* wvb = wkb + N_WK;
  unsigned short* wob = wvb + N_WK;
  unsigned short* Qb  = wob + N_WQ;
  unsigned short* Kb  = Qb  + N_Q;
  unsigned short* VTb = Kb  + N_K;
  unsigned short* AOb = VTb + N_K;

  cast_all_kernel<<<dim3(9216), dim3(256), 0, stream>>>(
      x, wq, wk, wv, wo, xb, wqb, wkb, wvb, wob);

  gemm_qkv<<<dim3(768), 256, 0, stream>>>(xb, wqb, wkb, wvb, Qb, Kb, VTb);
  attn_kernel<<<dim3(512, 1, 1), 256, 0, stream>>>(Qb, Kb, VTb, AOb);
  gemm_bt<false><<<dim3(32, 16, 1), 256, 0, stream>>>(AOb, wob, out, 2048, DMODEL);
}